// Round 2
// baseline (1316.326 us; speedup 1.0000x reference)
//
#include <hip/hip_runtime.h>
#include <hip/hip_bf16.h>
#include <type_traits>

// ---------------------------------------------------------------------------
// VanillaLSTM forward, persistent-RNN style. FP32 global I/O, bf16 MFMA core.
// B=4096 seqs / 256 blocks -> 16 rows per block, one block per CU.
// 512 threads = 8 waves; wave w owns cell-channel slice [w*16, w*16+16).
// Weights-stationary in VGPRs/AGPRs (pins the CU at 8 waves -- structural).
//
// Round 9 change vs round 8 (why round 8 was neutral: source-level interleave
// of the 16 Wih.e_{u+1} MFMAs into the trans chain did NOT survive compilation
// -- MfmaUtil stayed 37.8%, VALUBusy 47%, still time-serialized pipes):
//  * PIN the interleave with sched_group_barrier. A sched_barrier(0) scopes
//    the region (keeps the Whh-chain MFMAs out of the pin list), then each
//    r-iteration pins 4 x [(MFMA,1),(VALU,~6)]: one Wih MFMA per ~6
//    VALU/trans ops. 32 Wih MFMAs/SIMD (~620 cyc matrix) hide under the
//    ~1100 cyc trans phase instead of extending the MFMA burst.
//    Dataflow identical to round 8 -> bitwise-identical results.
// ---------------------------------------------------------------------------

#define B_TOT 4096
#define T_LEN 1024
#define D_INP 2
#define EMD   128
#define CELL  128
#define D_OUT 5

#define ROWS  16               // batch rows per block (MFMA N)
#define WAVES 8
#define BLOCK (WAVES * 64)
#define LDH   136              // padded LDS row stride in shorts

typedef short s8v  __attribute__((ext_vector_type(8)));   // 8 x bf16 MFMA frag
typedef float f32x4 __attribute__((ext_vector_type(4)));

#define BAR() asm volatile("s_waitcnt lgkmcnt(0)\n\ts_barrier" ::: "memory")
#define MFMA_BF16(A, B, C) __builtin_amdgcn_mfma_f32_16x16x32_bf16((A), (B), (C), 0, 0, 0)
// sched_group_barrier masks (LLVM SchedGroupMask): VALU=0x2, MFMA=0x8
#define SGB(mask, n) __builtin_amdgcn_sched_group_barrier((mask), (n), 0)

#if __has_builtin(__builtin_amdgcn_exp2f)
#define EXP2F(x) __builtin_amdgcn_exp2f(x)
#else
#define EXP2F(x) exp2f(x)
#endif
#if __has_builtin(__builtin_amdgcn_rcpf)
#define RCPF(x) __builtin_amdgcn_rcpf(x)
#else
#define RCPF(x) (1.0f / (x))
#endif

__device__ __forceinline__ short f2bf(float f) {   // RNE (init-time only)
    unsigned int u = __builtin_bit_cast(unsigned int, f);
    u += 0x7fffu + ((u >> 16) & 1u);
    return (short)(u >> 16);
}
// pack two fp32 -> two bf16 in one dword (low16 = a), round-nearest ties-away
__device__ __forceinline__ unsigned int pk2(float a, float b) {
    unsigned int ua = __builtin_bit_cast(unsigned int, a) + 0x8000u;
    unsigned int ub = __builtin_bit_cast(unsigned int, b) + 0x8000u;
    return __builtin_amdgcn_perm(ub, ua, 0x07060302);  // {ub.hi16, ua.hi16}
}
__device__ __forceinline__ s8v load8_scaled(const float* p, float s) {
    float4 a = *(const float4*)p;
    float4 b = *(const float4*)(p + 4);
    s8v r;
    r[0] = f2bf(a.x * s); r[1] = f2bf(a.y * s); r[2] = f2bf(a.z * s); r[3] = f2bf(a.w * s);
    r[4] = f2bf(b.x * s); r[5] = f2bf(b.y * s); r[6] = f2bf(b.z * s); r[7] = f2bf(b.w * s);
    return r;
}

__global__ __launch_bounds__(BLOCK, 1)
void lstm_persistent(const float* __restrict__ x,     // [B,T,2]
                     const float* __restrict__ We,    // [128,2]
                     const float* __restrict__ be,    // [128]
                     const float* __restrict__ Wih,   // [512,128]
                     const float* __restrict__ Whh,   // [512,128]
                     const float* __restrict__ bih,   // [512]
                     const float* __restrict__ bhh,   // [512]
                     const float* __restrict__ Wo,    // [5,128]
                     const float* __restrict__ bo,    // [5]
                     float* __restrict__ out)         // y[B,T,5] | h[B,128] | c[B,128]
{
    __shared__ short h_lds[2][ROWS][LDH];   // [row][channel], bf16
    __shared__ short e_lds[2][ROWS][LDH];

    const int tid  = threadIdx.x;
    const int lane = tid & 63;
    const int w    = tid >> 6;         // wave 0..7
    const int n16  = lane & 15;        // B-operand index: batch row
    const int q    = lane >> 4;        // quad 0..3
    const int q8   = q * 8;
    const int b0   = blockIdx.x * ROWS;
    const int ch0  = w * 16 + q * 4;   // first of this lane's 4 channels

    float* out_y = out;
    float* out_h = out + (size_t)B_TOT * T_LEN * D_OUT;
    float* out_c = out_h + (size_t)B_TOT * CELL;

    // gate pre-scales: sigm gates -log2(e), tanh gate -2*log2(e)
    const float GSC[4] = {-1.44269504f, -1.44269504f, -2.88539008f, -1.44269504f};

    // ---- persistent weight fragments, A-operand layout A[m][k]:
    //      m = lane&15 -> channel (w*16+n16), k = q*8+j ----
    s8v wih_f[4][4], whh_f[4][4];      // [gate i/f/g/o][ktile]
    #pragma unroll
    for (int g = 0; g < 4; ++g) {
        const int row = g * CELL + w * 16 + n16;
        #pragma unroll
        for (int kt = 0; kt < 4; ++kt) {
            wih_f[g][kt] = load8_scaled(Wih + row * EMD  + kt * 32 + q8, GSC[g]);
            whh_f[g][kt] = load8_scaled(Whh + row * CELL + kt * 32 + q8, GSC[g]);
        }
    }
    // per-lane pre-scaled biases for its 4 channels (C/D row q*4+r -> ch0+r)
    f32x4 bias_v[4];
    #pragma unroll
    for (int g = 0; g < 4; ++g) {
        float4 bi = *(const float4*)(bih + g * CELL + ch0);
        float4 bh = *(const float4*)(bhh + g * CELL + ch0);
        bias_v[g] = f32x4{(bi.x + bh.x) * GSC[g], (bi.y + bh.y) * GSC[g],
                          (bi.z + bh.z) * GSC[g], (bi.w + bh.w) * GSC[g]};
    }

    // ---- wave 0: output projection (unscaled). m=lane&15 -> out-channel ----
    s8v wo_f[4];
    f32x4 bo_v;
    {
        s8v z = {0, 0, 0, 0, 0, 0, 0, 0};
        #pragma unroll
        for (int kt = 0; kt < 4; ++kt) wo_f[kt] = z;
        if (w == 0 && n16 < D_OUT) {
            #pragma unroll
            for (int kt = 0; kt < 4; ++kt)
                wo_f[kt] = load8_scaled(Wo + n16 * CELL + kt * 32 + q8, 1.0f);
        }
        #pragma unroll
        for (int r = 0; r < 4; ++r) {
            const int oc = q * 4 + r;
            bo_v[r] = (w == 0 && oc < D_OUT) ? bo[oc] : 0.0f;
        }
    }

    // ---- embedding constants: thread handles row er, e-cols jj0..jj0+3 ----
    const int er  = tid >> 5;           // 0..15
    const int jj0 = (tid & 31) * 4;     // 0..124
    float weA[4], weB[4], bev[4];
    #pragma unroll
    for (int jl = 0; jl < 4; ++jl) {
        weA[jl] = We[(jj0 + jl) * 2 + 0];
        weB[jl] = We[(jj0 + jl) * 2 + 1];
        bev[jl] = be[jj0 + jl];
    }
    const float* xrow = x + (size_t)(b0 + er) * T_LEN * D_INP;

    auto embed = [&](int t, short (*ebuf)[LDH]) {
        float2 xd = *(const float2*)(xrow + t * D_INP);
        float e0 = fmaxf(xd.x * weA[0] + xd.y * weB[0] + bev[0], 0.0f);
        float e1 = fmaxf(xd.x * weA[1] + xd.y * weB[1] + bev[1], 0.0f);
        float e2 = fmaxf(xd.x * weA[2] + xd.y * weB[2] + bev[2], 0.0f);
        float e3 = fmaxf(xd.x * weA[3] + xd.y * weB[3] + bev[3], 0.0f);
        unsigned int* ep = (unsigned int*)&ebuf[er][jj0];
        ep[0] = pk2(e0, e1); ep[1] = pk2(e2, e3);
    };

    // ---- prologue: h_0 = 0; e_0 -> e_lds[1] (scratch) ----
    {
        unsigned int* hz = (unsigned int*)&h_lds[0][0][0];
        for (int i = tid; i < ROWS * LDH / 2; i += BLOCK) hz[i] = 0u;
        embed(0, e_lds[1]);
    }
    BAR();

    // acc_e[g] = bias + Wih.e_0 (for step 0); then e_1 -> e_lds[0]
    f32x4 acc_e[4];
    {
        s8v ae0[4];
        #pragma unroll
        for (int kt = 0; kt < 4; ++kt)
            ae0[kt] = *(const s8v*)&e_lds[1][n16][kt * 32 + q8];
        #pragma unroll
        for (int g = 0; g < 4; ++g) {
            f32x4 a = MFMA_BF16(wih_f[g][0], ae0[0], bias_v[g]);
            a = MFMA_BF16(wih_f[g][1], ae0[1], a);
            a = MFMA_BF16(wih_f[g][2], ae0[2], a);
            a = MFMA_BF16(wih_f[g][3], ae0[3], a);
            acc_e[g] = a;
        }
        embed(1, e_lds[0]);
    }

    float c_r[4] = {0.0f, 0.0f, 0.0f, 0.0f};

    // ======================= time loop, unrolled x2 =======================
    // Invariant at BAR of step u (P=u&1): h_lds[P] = h_u, e_lds[P] = e_{u+1},
    // acc_e[] = bias + Wih.e_u. Step u: finish gates with Whh.h_u, produce
    // h_{u+1} -> h_lds[1-P], acc_e' = bias + Wih.e_{u+1}, e_{u+2} -> e_lds[1-P].
    auto step = [&](int u, auto Pc) {
        constexpr int P = decltype(Pc)::value;
        BAR();   // lgkm-only: h_lds[P], e_lds[P] visible; our prior reads drained

        s8v ah[4], ae[4];
        #pragma unroll
        for (int kt = 0; kt < 4; ++kt) {
            ah[kt] = *(const s8v*)&h_lds[P][n16][kt * 32 + q8];
            ae[kt] = *(const s8v*)&e_lds[P][n16][kt * 32 + q8];
        }

        // wave 0: ISSUE y_{u-1} = Wo @ h_u^T early; store at end of step.
        const bool ydo = (w == 0) && (u > 0);
        f32x4 ay;
        if (ydo) {
            ay = MFMA_BF16(wo_f[0], ah[0], bo_v);
            ay = MFMA_BF16(wo_f[1], ah[1], ay);
            ay = MFMA_BF16(wo_f[2], ah[2], ay);
            ay = MFMA_BF16(wo_f[3], ah[3], ay);
        }

        // finish gates: acc[g] = acc_e[g] + Whh.h_u  (16 MFMAs)
        f32x4 acc[4];
        #pragma unroll
        for (int g = 0; g < 4; ++g) {
            f32x4 a = MFMA_BF16(whh_f[g][0], ah[0], acc_e[g]);
            a = MFMA_BF16(whh_f[g][1], ah[1], a);
            a = MFMA_BF16(whh_f[g][2], ah[2], a);
            a = MFMA_BF16(whh_f[g][3], ah[3], a);
            acc[g] = a;
        }

        // Scope the scheduling region: keep the Whh-chain MFMAs above out of
        // the r-loop's pinned groups (nothing crosses this point).
        __builtin_amdgcn_sched_barrier(0);

        // interleave: element-r trans chain (7 trans) with gate-r's 4-MFMA
        // Wih.e_{u+1} chain -- PINNED via sched_group_barrier so the emitted
        // schedule alternates 1 MFMA : ~6 VALU (trans included in VALU mask).
        float hv[4];
        #pragma unroll
        for (int r = 0; r < 4; ++r) {
            f32x4 a = MFMA_BF16(wih_f[r][0], ae[0], bias_v[r]);
            float ti = EXP2F(acc[0][r]);
            float tf = EXP2F(acc[1][r]);
            float tg = EXP2F(acc[2][r]);
            float to = EXP2F(acc[3][r]);
            a = MFMA_BF16(wih_f[r][1], ae[1], a);
            float pig = (1.0f + ti) * (1.0f + tg);
            float pf  = 1.0f + tf;
            float num = c_r[r] * pig + pf * (1.0f - tg);
            float rd  = RCPF(pf * pig);
            a = MFMA_BF16(wih_f[r][2], ae[2], a);
            float cn  = num * rd;
            c_r[r] = cn;
            float tc = EXP2F(-2.88539008f * cn);
            a = MFMA_BF16(wih_f[r][3], ae[3], a);
            float rh = RCPF((1.0f + to) * (1.0f + tc));
            hv[r] = (1.0f - tc) * rh;
            acc_e[r] = a;
            // pin: 4 x [1 MFMA, ~6 VALU] per element
            SGB(0x8, 1); SGB(0x2, 6);
            SGB(0x8, 1); SGB(0x2, 6);
            SGB(0x8, 1); SGB(0x2, 6);
            SGB(0x8, 1); SGB(0x2, 5);
        }

        {   // h_{u+1}: 4 consecutive bf16 = one 8B LDS write
            unsigned int* hp = (unsigned int*)&h_lds[1 - P][n16][ch0];
            hp[0] = pk2(hv[0], hv[1]); hp[1] = pk2(hv[2], hv[3]);
        }
        if (u == T_LEN - 1) {   // final h, fp32 from registers (uniform branch)
            *(float4*)(out_h + (size_t)(b0 + n16) * CELL + ch0) =
                make_float4(hv[0], hv[1], hv[2], hv[3]);
        }
        // e_{u+2} into the other buffer (wraps to dummy x reads at the tail)
        embed((u + 2) & (T_LEN - 1), e_lds[1 - P]);

        // y store, long after its MFMA chain completed (streams; no vmcnt wait)
        if (ydo) {
            float* yp = out_y + ((size_t)(b0 + n16) * T_LEN + (u - 1)) * D_OUT;
            if (q == 0) { yp[0] = ay[0]; yp[1] = ay[1]; yp[2] = ay[2]; yp[3] = ay[3]; }
            else if (q == 1) { yp[4] = ay[0]; }
        }
    };

    #pragma unroll 1
    for (int u = 0; u < T_LEN; u += 2) {
        step(u,     std::integral_constant<int, 0>{});
        step(u + 1, std::integral_constant<int, 1>{});
    }

    // ======================= epilogue =======================
    BAR();   // h_T lives in h_lds[0] (iter 1023 wrote buffer 0)

    if (w == 0) {   // y_{T-1} = Wo @ h_T^T
        s8v ah[4];
        #pragma unroll
        for (int kt = 0; kt < 4; ++kt)
            ah[kt] = *(const s8v*)&h_lds[0][n16][kt * 32 + q8];
        f32x4 ay = MFMA_BF16(wo_f[0], ah[0], bo_v);
        ay = MFMA_BF16(wo_f[1], ah[1], ay);
        ay = MFMA_BF16(wo_f[2], ah[2], ay);
        ay = MFMA_BF16(wo_f[3], ah[3], ay);
        float* yp = out_y + ((size_t)(b0 + n16) * T_LEN + (T_LEN - 1)) * D_OUT;
        if (q == 0) {
            yp[0] = ay[0]; yp[1] = ay[1]; yp[2] = ay[2]; yp[3] = ay[3];
        } else if (q == 1) {
            yp[4] = ay[0];
        }
    }

    // final c: 4 consecutive channels -> one float4 store
    *(float4*)(out_c + (size_t)(b0 + n16) * CELL + ch0) =
        make_float4(c_r[0], c_r[1], c_r[2], c_r[3]);
}

extern "C" void kernel_launch(void* const* d_in, const int* in_sizes, int n_in,
                              void* d_out, int out_size, void* d_ws, size_t ws_size,
                              hipStream_t stream) {
    const float* x   = (const float*)d_in[0];
    const float* We  = (const float*)d_in[1];
    const float* be  = (const float*)d_in[2];
    const float* Wih = (const float*)d_in[3];
    const float* Whh = (const float*)d_in[4];
    const float* bih = (const float*)d_in[5];
    const float* bhh = (const float*)d_in[6];
    const float* Wo  = (const float*)d_in[7];
    const float* bo  = (const float*)d_in[8];
    float* out = (float*)d_out;

    dim3 grid(B_TOT / ROWS);   // 256 blocks, one per CU
    dim3 block(BLOCK);         // 512 threads = 8 waves
    hipLaunchKernelGGL(lstm_persistent, grid, block, 0, stream,
                       x, We, be, Wih, Whh, bih, bhh, Wo, bo, out);
}

// Round 3
// 1204.588 us; speedup vs baseline: 1.0928x; 1.0928x over previous
//
#include <hip/hip_runtime.h>
#include <hip/hip_bf16.h>
#include <type_traits>

// ---------------------------------------------------------------------------
// VanillaLSTM forward, persistent-RNN style. FP32 global I/O, bf16 MFMA core.
// B=4096 seqs / 256 blocks -> 16 rows per block, one block per CU.
// 512 threads = 8 waves; wave w owns cell-channel slice [w*16, w*16+16).
// Weights-stationary in VGPRs/AGPRs (pins the CU at 8 waves -- structural).
//
// Round 10 change vs round 9 (why round 9 REGRESSED -5%: the 1:6 pin used the
// r-loop's SERIAL per-gate MFMA chains -> every pinned MFMA stalled on its
// predecessor (~20 cyc each); and sched_barrier(0) trapped embed's global
// load next to its use (+~200 cyc L2 bubble)):
//  * Breadth-first Wih emission: kt-outer/gate-inner order. Adjacent pinned
//    MFMAs belong to different accumulator chains (dependent distance = 4
//    slots > MFMA latency). Per-chain accumulation order unchanged ->
//    bitwise-identical results.
//  * Pin 16 x [(MFMA,1),(VALU,5)]: 80 <= ~84 VALU/trans ops in region, so
//    no group starves (round 9's x6 starved the tail).
//  * x prefetch at step top: the global load issues before the Whh phase,
//    its latency spans the step regardless of sched fences.
// ---------------------------------------------------------------------------

#define B_TOT 4096
#define T_LEN 1024
#define D_INP 2
#define EMD   128
#define CELL  128
#define D_OUT 5

#define ROWS  16               // batch rows per block (MFMA N)
#define WAVES 8
#define BLOCK (WAVES * 64)
#define LDH   136              // padded LDS row stride in shorts

typedef short s8v  __attribute__((ext_vector_type(8)));   // 8 x bf16 MFMA frag
typedef float f32x4 __attribute__((ext_vector_type(4)));

#define BAR() asm volatile("s_waitcnt lgkmcnt(0)\n\ts_barrier" ::: "memory")
#define MFMA_BF16(A, B, C) __builtin_amdgcn_mfma_f32_16x16x32_bf16((A), (B), (C), 0, 0, 0)
// sched_group_barrier masks (LLVM SchedGroupMask): VALU=0x2, MFMA=0x8
#define SGB(mask, n) __builtin_amdgcn_sched_group_barrier((mask), (n), 0)

#if __has_builtin(__builtin_amdgcn_exp2f)
#define EXP2F(x) __builtin_amdgcn_exp2f(x)
#else
#define EXP2F(x) exp2f(x)
#endif
#if __has_builtin(__builtin_amdgcn_rcpf)
#define RCPF(x) __builtin_amdgcn_rcpf(x)
#else
#define RCPF(x) (1.0f / (x))
#endif

__device__ __forceinline__ short f2bf(float f) {   // RNE (init-time only)
    unsigned int u = __builtin_bit_cast(unsigned int, f);
    u += 0x7fffu + ((u >> 16) & 1u);
    return (short)(u >> 16);
}
// pack two fp32 -> two bf16 in one dword (low16 = a), round-nearest ties-away
__device__ __forceinline__ unsigned int pk2(float a, float b) {
    unsigned int ua = __builtin_bit_cast(unsigned int, a) + 0x8000u;
    unsigned int ub = __builtin_bit_cast(unsigned int, b) + 0x8000u;
    return __builtin_amdgcn_perm(ub, ua, 0x07060302);  // {ub.hi16, ua.hi16}
}
__device__ __forceinline__ s8v load8_scaled(const float* p, float s) {
    float4 a = *(const float4*)p;
    float4 b = *(const float4*)(p + 4);
    s8v r;
    r[0] = f2bf(a.x * s); r[1] = f2bf(a.y * s); r[2] = f2bf(a.z * s); r[3] = f2bf(a.w * s);
    r[4] = f2bf(b.x * s); r[5] = f2bf(b.y * s); r[6] = f2bf(b.z * s); r[7] = f2bf(b.w * s);
    return r;
}

__global__ __launch_bounds__(BLOCK, 1)
void lstm_persistent(const float* __restrict__ x,     // [B,T,2]
                     const float* __restrict__ We,    // [128,2]
                     const float* __restrict__ be,    // [128]
                     const float* __restrict__ Wih,   // [512,128]
                     const float* __restrict__ Whh,   // [512,128]
                     const float* __restrict__ bih,   // [512]
                     const float* __restrict__ bhh,   // [512]
                     const float* __restrict__ Wo,    // [5,128]
                     const float* __restrict__ bo,    // [5]
                     float* __restrict__ out)         // y[B,T,5] | h[B,128] | c[B,128]
{
    __shared__ short h_lds[2][ROWS][LDH];   // [row][channel], bf16
    __shared__ short e_lds[2][ROWS][LDH];

    const int tid  = threadIdx.x;
    const int lane = tid & 63;
    const int w    = tid >> 6;         // wave 0..7
    const int n16  = lane & 15;        // B-operand index: batch row
    const int q    = lane >> 4;        // quad 0..3
    const int q8   = q * 8;
    const int b0   = blockIdx.x * ROWS;
    const int ch0  = w * 16 + q * 4;   // first of this lane's 4 channels

    float* out_y = out;
    float* out_h = out + (size_t)B_TOT * T_LEN * D_OUT;
    float* out_c = out_h + (size_t)B_TOT * CELL;

    // gate pre-scales: sigm gates -log2(e), tanh gate -2*log2(e)
    const float GSC[4] = {-1.44269504f, -1.44269504f, -2.88539008f, -1.44269504f};

    // ---- persistent weight fragments, A-operand layout A[m][k]:
    //      m = lane&15 -> channel (w*16+n16), k = q*8+j ----
    s8v wih_f[4][4], whh_f[4][4];      // [gate i/f/g/o][ktile]
    #pragma unroll
    for (int g = 0; g < 4; ++g) {
        const int row = g * CELL + w * 16 + n16;
        #pragma unroll
        for (int kt = 0; kt < 4; ++kt) {
            wih_f[g][kt] = load8_scaled(Wih + row * EMD  + kt * 32 + q8, GSC[g]);
            whh_f[g][kt] = load8_scaled(Whh + row * CELL + kt * 32 + q8, GSC[g]);
        }
    }
    // per-lane pre-scaled biases for its 4 channels (C/D row q*4+r -> ch0+r)
    f32x4 bias_v[4];
    #pragma unroll
    for (int g = 0; g < 4; ++g) {
        float4 bi = *(const float4*)(bih + g * CELL + ch0);
        float4 bh = *(const float4*)(bhh + g * CELL + ch0);
        bias_v[g] = f32x4{(bi.x + bh.x) * GSC[g], (bi.y + bh.y) * GSC[g],
                          (bi.z + bh.z) * GSC[g], (bi.w + bh.w) * GSC[g]};
    }

    // ---- wave 0: output projection (unscaled). m=lane&15 -> out-channel ----
    s8v wo_f[4];
    f32x4 bo_v;
    {
        s8v z = {0, 0, 0, 0, 0, 0, 0, 0};
        #pragma unroll
        for (int kt = 0; kt < 4; ++kt) wo_f[kt] = z;
        if (w == 0 && n16 < D_OUT) {
            #pragma unroll
            for (int kt = 0; kt < 4; ++kt)
                wo_f[kt] = load8_scaled(Wo + n16 * CELL + kt * 32 + q8, 1.0f);
        }
        #pragma unroll
        for (int r = 0; r < 4; ++r) {
            const int oc = q * 4 + r;
            bo_v[r] = (w == 0 && oc < D_OUT) ? bo[oc] : 0.0f;
        }
    }

    // ---- embedding constants: thread handles row er, e-cols jj0..jj0+3 ----
    const int er  = tid >> 5;           // 0..15
    const int jj0 = (tid & 31) * 4;     // 0..124
    float weA[4], weB[4], bev[4];
    #pragma unroll
    for (int jl = 0; jl < 4; ++jl) {
        weA[jl] = We[(jj0 + jl) * 2 + 0];
        weB[jl] = We[(jj0 + jl) * 2 + 1];
        bev[jl] = be[jj0 + jl];
    }
    const float* xrow = x + (size_t)(b0 + er) * T_LEN * D_INP;

    auto embed = [&](float2 xd, short (*ebuf)[LDH]) {
        float e0 = fmaxf(xd.x * weA[0] + xd.y * weB[0] + bev[0], 0.0f);
        float e1 = fmaxf(xd.x * weA[1] + xd.y * weB[1] + bev[1], 0.0f);
        float e2 = fmaxf(xd.x * weA[2] + xd.y * weB[2] + bev[2], 0.0f);
        float e3 = fmaxf(xd.x * weA[3] + xd.y * weB[3] + bev[3], 0.0f);
        unsigned int* ep = (unsigned int*)&ebuf[er][jj0];
        ep[0] = pk2(e0, e1); ep[1] = pk2(e2, e3);
    };

    // ---- prologue: h_0 = 0; e_0 -> e_lds[1] (scratch) ----
    {
        unsigned int* hz = (unsigned int*)&h_lds[0][0][0];
        for (int i = tid; i < ROWS * LDH / 2; i += BLOCK) hz[i] = 0u;
        embed(*(const float2*)(xrow), e_lds[1]);
    }
    BAR();

    // acc_e[g] = bias + Wih.e_0 (for step 0); then e_1 -> e_lds[0]
    f32x4 acc_e[4];
    {
        s8v ae0[4];
        #pragma unroll
        for (int kt = 0; kt < 4; ++kt)
            ae0[kt] = *(const s8v*)&e_lds[1][n16][kt * 32 + q8];
        #pragma unroll
        for (int g = 0; g < 4; ++g) {
            f32x4 a = MFMA_BF16(wih_f[g][0], ae0[0], bias_v[g]);
            a = MFMA_BF16(wih_f[g][1], ae0[1], a);
            a = MFMA_BF16(wih_f[g][2], ae0[2], a);
            a = MFMA_BF16(wih_f[g][3], ae0[3], a);
            acc_e[g] = a;
        }
        embed(*(const float2*)(xrow + 1 * D_INP), e_lds[0]);
    }

    float c_r[4] = {0.0f, 0.0f, 0.0f, 0.0f};

    // ======================= time loop, unrolled x2 =======================
    // Invariant at BAR of step u (P=u&1): h_lds[P] = h_u, e_lds[P] = e_{u+1},
    // acc_e[] = bias + Wih.e_u. Step u: finish gates with Whh.h_u, produce
    // h_{u+1} -> h_lds[1-P], acc_e' = bias + Wih.e_{u+1}, e_{u+2} -> e_lds[1-P].
    auto step = [&](int u, auto Pc) {
        constexpr int P = decltype(Pc)::value;
        BAR();   // lgkm-only: h_lds[P], e_lds[P] visible; our prior reads drained

        // x prefetch for embed(u+2): issue the global load at step top so its
        // latency spans the whole step (sched fences below can't trap it).
        float2 xd = *(const float2*)(xrow + ((u + 2) & (T_LEN - 1)) * D_INP);

        s8v ah[4], ae[4];
        #pragma unroll
        for (int kt = 0; kt < 4; ++kt) {
            ah[kt] = *(const s8v*)&h_lds[P][n16][kt * 32 + q8];
            ae[kt] = *(const s8v*)&e_lds[P][n16][kt * 32 + q8];
        }

        // wave 0: ISSUE y_{u-1} = Wo @ h_u^T early; store at end of step.
        const bool ydo = (w == 0) && (u > 0);
        f32x4 ay;
        if (ydo) {
            ay = MFMA_BF16(wo_f[0], ah[0], bo_v);
            ay = MFMA_BF16(wo_f[1], ah[1], ay);
            ay = MFMA_BF16(wo_f[2], ah[2], ay);
            ay = MFMA_BF16(wo_f[3], ah[3], ay);
        }

        // finish gates: acc[g] = acc_e[g] + Whh.h_u  (16 MFMAs)
        f32x4 acc[4];
        #pragma unroll
        for (int g = 0; g < 4; ++g) {
            f32x4 a = MFMA_BF16(whh_f[g][0], ah[0], acc_e[g]);
            a = MFMA_BF16(whh_f[g][1], ah[1], a);
            a = MFMA_BF16(whh_f[g][2], ah[2], a);
            a = MFMA_BF16(whh_f[g][3], ah[3], a);
            acc[g] = a;
        }

        // Scope the scheduling region: keep the Whh-chain MFMAs above out of
        // the pinned groups below.
        __builtin_amdgcn_sched_barrier(0);

        // --- overlap region: 16 Wih.e_{u+1} MFMAs, breadth-first (kt-outer,
        //     gate-inner: adjacent MFMAs are from different chains), plus the
        //     4 independent element trans chains. Pinned 1 MFMA : 5 VALU. ---
        f32x4 na0 = MFMA_BF16(wih_f[0][0], ae[0], bias_v[0]);
        f32x4 na1 = MFMA_BF16(wih_f[1][0], ae[0], bias_v[1]);
        f32x4 na2 = MFMA_BF16(wih_f[2][0], ae[0], bias_v[2]);
        f32x4 na3 = MFMA_BF16(wih_f[3][0], ae[0], bias_v[3]);
        na0 = MFMA_BF16(wih_f[0][1], ae[1], na0);
        na1 = MFMA_BF16(wih_f[1][1], ae[1], na1);
        na2 = MFMA_BF16(wih_f[2][1], ae[1], na2);
        na3 = MFMA_BF16(wih_f[3][1], ae[1], na3);
        na0 = MFMA_BF16(wih_f[0][2], ae[2], na0);
        na1 = MFMA_BF16(wih_f[1][2], ae[2], na1);
        na2 = MFMA_BF16(wih_f[2][2], ae[2], na2);
        na3 = MFMA_BF16(wih_f[3][2], ae[2], na3);
        na0 = MFMA_BF16(wih_f[0][3], ae[3], na0);
        na1 = MFMA_BF16(wih_f[1][3], ae[3], na1);
        na2 = MFMA_BF16(wih_f[2][3], ae[3], na2);
        na3 = MFMA_BF16(wih_f[3][3], ae[3], na3);

        // elementwise, combined-reciprocal form (7 trans/element):
        float hv[4];
        #pragma unroll
        for (int r = 0; r < 4; ++r) {
            float ti = EXP2F(acc[0][r]);
            float tf = EXP2F(acc[1][r]);
            float tg = EXP2F(acc[2][r]);
            float to = EXP2F(acc[3][r]);
            float pig = (1.0f + ti) * (1.0f + tg);
            float pf  = 1.0f + tf;
            float num = c_r[r] * pig + pf * (1.0f - tg);
            float rd  = RCPF(pf * pig);
            float cn  = num * rd;
            c_r[r] = cn;
            float tc = EXP2F(-2.88539008f * cn);
            float rh = RCPF((1.0f + to) * (1.0f + tc));
            hv[r] = (1.0f - tc) * rh;
        }
        acc_e[0] = na0; acc_e[1] = na1; acc_e[2] = na2; acc_e[3] = na3;

        // pin: 16 x [1 MFMA, 5 VALU] (trans counts as VALU). Adjacent MFMAs
        // are chain-independent -> no dependent-latency stalls in the slots.
        SGB(0x8, 1); SGB(0x2, 5);  SGB(0x8, 1); SGB(0x2, 5);
        SGB(0x8, 1); SGB(0x2, 5);  SGB(0x8, 1); SGB(0x2, 5);
        SGB(0x8, 1); SGB(0x2, 5);  SGB(0x8, 1); SGB(0x2, 5);
        SGB(0x8, 1); SGB(0x2, 5);  SGB(0x8, 1); SGB(0x2, 5);
        SGB(0x8, 1); SGB(0x2, 5);  SGB(0x8, 1); SGB(0x2, 5);
        SGB(0x8, 1); SGB(0x2, 5);  SGB(0x8, 1); SGB(0x2, 5);
        SGB(0x8, 1); SGB(0x2, 5);  SGB(0x8, 1); SGB(0x2, 5);
        SGB(0x8, 1); SGB(0x2, 5);  SGB(0x8, 1); SGB(0x2, 5);
        __builtin_amdgcn_sched_barrier(0);

        {   // h_{u+1}: 4 consecutive bf16 = one 8B LDS write
            unsigned int* hp = (unsigned int*)&h_lds[1 - P][n16][ch0];
            hp[0] = pk2(hv[0], hv[1]); hp[1] = pk2(hv[2], hv[3]);
        }
        if (u == T_LEN - 1) {   // final h, fp32 from registers (uniform branch)
            *(float4*)(out_h + (size_t)(b0 + n16) * CELL + ch0) =
                make_float4(hv[0], hv[1], hv[2], hv[3]);
        }
        // e_{u+2} into the other buffer (x already in registers)
        embed(xd, e_lds[1 - P]);

        // y store, long after its MFMA chain completed (streams; no vmcnt wait)
        if (ydo) {
            float* yp = out_y + ((size_t)(b0 + n16) * T_LEN + (u - 1)) * D_OUT;
            if (q == 0) { yp[0] = ay[0]; yp[1] = ay[1]; yp[2] = ay[2]; yp[3] = ay[3]; }
            else if (q == 1) { yp[4] = ay[0]; }
        }
    };

    #pragma unroll 1
    for (int u = 0; u < T_LEN; u += 2) {
        step(u,     std::integral_constant<int, 0>{});
        step(u + 1, std::integral_constant<int, 1>{});
    }

    // ======================= epilogue =======================
    BAR();   // h_T lives in h_lds[0] (iter 1023 wrote buffer 0)

    if (w == 0) {   // y_{T-1} = Wo @ h_T^T
        s8v ah[4];
        #pragma unroll
        for (int kt = 0; kt < 4; ++kt)
            ah[kt] = *(const s8v*)&h_lds[0][n16][kt * 32 + q8];
        f32x4 ay = MFMA_BF16(wo_f[0], ah[0], bo_v);
        ay = MFMA_BF16(wo_f[1], ah[1], ay);
        ay = MFMA_BF16(wo_f[2], ah[2], ay);
        ay = MFMA_BF16(wo_f[3], ah[3], ay);
        float* yp = out_y + ((size_t)(b0 + n16) * T_LEN + (T_LEN - 1)) * D_OUT;
        if (q == 0) {
            yp[0] = ay[0]; yp[1] = ay[1]; yp[2] = ay[2]; yp[3] = ay[3];
        } else if (q == 1) {
            yp[4] = ay[0];
        }
    }

    // final c: 4 consecutive channels -> one float4 store
    *(float4*)(out_c + (size_t)(b0 + n16) * CELL + ch0) =
        make_float4(c_r[0], c_r[1], c_r[2], c_r[3]);
}

extern "C" void kernel_launch(void* const* d_in, const int* in_sizes, int n_in,
                              void* d_out, int out_size, void* d_ws, size_t ws_size,
                              hipStream_t stream) {
    const float* x   = (const float*)d_in[0];
    const float* We  = (const float*)d_in[1];
    const float* be  = (const float*)d_in[2];
    const float* Wih = (const float*)d_in[3];
    const float* Whh = (const float*)d_in[4];
    const float* bih = (const float*)d_in[5];
    const float* bhh = (const float*)d_in[6];
    const float* Wo  = (const float*)d_in[7];
    const float* bo  = (const float*)d_in[8];
    float* out = (float*)d_out;

    dim3 grid(B_TOT / ROWS);   // 256 blocks, one per CU
    dim3 block(BLOCK);         // 512 threads = 8 waves
    hipLaunchKernelGGL(lstm_persistent, grid, block, 0, stream,
                       x, We, be, Wih, Whh, bih, bhh, Wo, bo, out);
}